// Round 1
// 337.374 us; speedup vs baseline: 1.0416x; 1.0416x over previous
//
#include <hip/hip_runtime.h>
#include <hip/hip_bf16.h>
#include <stdint.h>

#define B_   2
#define T_   2048
#define C_   2048
#define NH_  16
#define NKV_ 4
#define D_   128
#define NREP_ 4

typedef __attribute__((ext_vector_type(8))) short bf16x8;
typedef __attribute__((ext_vector_type(4))) float f32x4;

__device__ inline short f2bs(float f) {
    __hip_bfloat16 h = __float2bfloat16(f);
    return *reinterpret_cast<short*>(&h);
}
__device__ inline float bs2f(unsigned short s) {
    __hip_bfloat16 h = *reinterpret_cast<__hip_bfloat16*>(&s);
    return __bfloat162float(h);
}

__device__ inline void gl_lds16(const __hip_bfloat16* g, __hip_bfloat16* l) {
    __builtin_amdgcn_global_load_lds(
        (const __attribute__((address_space(1))) unsigned int*)g,
        (__attribute__((address_space(3))) unsigned int*)l,
        16, 0, 0);
}

// ---------------- fp32 -> bf16 convert ----------------
__global__ void cvt_f32_bf16(const float* __restrict__ src,
                             __hip_bfloat16* __restrict__ dst, int n) {
    int i = (blockIdx.x * blockDim.x + threadIdx.x) * 4;
    if (i >= n) return;
    float4 v = *reinterpret_cast<const float4*>(src + i);
    short4 o;
    o.x = f2bs(v.x); o.y = f2bs(v.y); o.z = f2bs(v.z); o.w = f2bs(v.w);
    *reinterpret_cast<short4*>(dst + i) = o;
}

// ---------------- bf16 GEMM: C = A @ B^T (m97 structure) ----------------
__device__ inline void storeC(float* p, float v) { *p = v; }
__device__ inline void storeC(__hip_bfloat16* p, float v) { *p = __float2bfloat16(v); }

template <typename OutT>
__global__ __launch_bounds__(256) void gemm_bt(const __hip_bfloat16* __restrict__ A,
                                               const __hip_bfloat16* __restrict__ Bm,
                                               OutT* __restrict__ Cm,
                                               int M, int N, int K) {
    __shared__ __hip_bfloat16 As[128 * 32];
    __shared__ __hip_bfloat16 Bs[128 * 32];
    const int tid  = threadIdx.x;
    const int lane = tid & 63;
    const int wv   = tid >> 6;
    const int m0 = blockIdx.y * 128, n0 = blockIdx.x * 128;
    const int wm = (wv >> 1) * 64, wn = (wv & 1) * 64;
    const int q16 = lane >> 4, r16 = lane & 15;

    f32x4 acc[4][4] = {};

    const int lrow = tid >> 2;
    const int lcol = (tid & 3) * 8;
    const __hip_bfloat16* aG = A  + (size_t)(m0 + lrow) * K + lcol;
    const __hip_bfloat16* bG = Bm + (size_t)(n0 + lrow) * K + lcol;
    __hip_bfloat16* aL = As + tid * 8;
    __hip_bfloat16* bL = Bs + tid * 8;

    for (int k0 = 0; k0 < K; k0 += 32) {
        __syncthreads();
        gl_lds16(aG + k0,          aL);
        gl_lds16(aG + 64 * K + k0, aL + 2048);
        gl_lds16(bG + k0,          bL);
        gl_lds16(bG + 64 * K + k0, bL + 2048);
        __syncthreads();
        bf16x8 af[4], bfr[4];
#pragma unroll
        for (int i = 0; i < 4; i++)
            af[i] = *reinterpret_cast<const bf16x8*>(As + (wm + i * 16 + r16) * 32 + q16 * 8);
#pragma unroll
        for (int j = 0; j < 4; j++)
            bfr[j] = *reinterpret_cast<const bf16x8*>(Bs + (wn + j * 16 + r16) * 32 + q16 * 8);
#pragma unroll
        for (int i = 0; i < 4; i++)
#pragma unroll
            for (int j = 0; j < 4; j++)
                acc[i][j] = __builtin_amdgcn_mfma_f32_16x16x32_bf16(af[i], bfr[j], acc[i][j], 0, 0, 0);
    }

#pragma unroll
    for (int i = 0; i < 4; i++)
#pragma unroll
        for (int j = 0; j < 4; j++)
#pragma unroll
            for (int r = 0; r < 4; r++) {
                int row = m0 + wm + i * 16 + q16 * 4 + r;
                int col = n0 + wn + j * 16 + r16;
                storeC(&Cm[(size_t)row * N + col], acc[i][j][r]);
            }
}

// ---------------- RoPE + scatter to attention layouts ----------------
__global__ void rope_scatter(const __hip_bfloat16* __restrict__ y,
                             __hip_bfloat16* __restrict__ qo,
                             __hip_bfloat16* __restrict__ ko,
                             __hip_bfloat16* __restrict__ vT) {
    int idx = blockIdx.x * blockDim.x + threadIdx.x;
    if (idx >= (B_ * T_) * 1536) return;
    int m = idx / 1536, pc = idx % 1536;
    int b = m / T_, t = m % T_;
    int n = pc * 2;
    ushort2 uv = *reinterpret_cast<const ushort2*>(y + (size_t)m * 3072 + n);
    float e = bs2f(uv.x), od = bs2f(uv.y);

    if (n < 2560) {  // q or k: apply RoPE
        int nn = (n < 2048) ? n : (n - 2048);
        int dloc = nn & 127;
        int p = dloc >> 1;
        float inv = __expf(-(float)p * (9.210340371976184f / 64.0f));  // 10000^(-p/64)
        float ang = (float)t * inv;
        float c = cosf(ang), s = sinf(ang);
        float re = e * c - od * s;
        float ro = e * s + od * c;
        ushort2 w;
        w.x = (unsigned short)f2bs(re);
        w.y = (unsigned short)f2bs(ro);
        if (n < 2048) {
            int h = n >> 7;
            *reinterpret_cast<ushort2*>(qo + ((size_t)(b * NH_ + h) * T_ + t) * D_ + dloc) = w;
        } else {
            int h = nn >> 7;
            *reinterpret_cast<ushort2*>(ko + ((size_t)(b * NKV_ + h) * T_ + t) * D_ + dloc) = w;
        }
    } else {  // v: no rope, store transposed (d, t)
        int nn = n - 2560;
        int h = nn >> 7, d = nn & 127;
        __hip_bfloat16* base = vT + (size_t)(b * NKV_ + h) * D_ * T_;
        base[(size_t)d * T_ + t]       = __float2bfloat16(e);
        base[(size_t)(d + 1) * T_ + t] = __float2bfloat16(od);
    }
}

// ---------------- flash attention, GQA-cooperative, 32 q-rows/wave ----------------
// Block = (b, g, 32-row t-tile). 4 waves = the 4 q-heads sharing KV group g.
// Per 32-s step the block stages K(8KB)+V(8KB) ONCE into LDS; each wave
// processes TWO 16-q tiles so the 8 K-frag reads feed 16 QK MFMAs and the
// 8 V-frag reads feed 16 PV MFMAs (shared across tiles) — ~2x arithmetic
// intensity per LDS byte vs 16-q/wave. m=0 flash softmax (scores O(1)).
//
// Load-balance note (R1): causal work per block is tb+1 iterations. The whole
// 512-block grid is co-resident (2 blocks/CU), so runtime = max over CUs of
// its pair's combined work. Round-robin dispatch puts ids i and i+256 (same
// blockIdx.x) on one CU; with tb = f(blockIdx.x) for BOTH halves, same-tb
// pairing made the tb=63 CU do 128 iters vs the 65-iter mean. Antisymmetric
// mapping below (first 4 bg slices descending, last 4 ascending) makes every
// CU pair sum to exactly 65 iterations.
__global__ __launch_bounds__(256, 3) void attn_kernel(const __hip_bfloat16* __restrict__ Q,
                                                      const __hip_bfloat16* __restrict__ Kt,
                                                      const __hip_bfloat16* __restrict__ Vt,
                                                      __hip_bfloat16* __restrict__ Ao) {
    __shared__ __hip_bfloat16 Ks[2][4096];   // 8 chunks x 512 shorts, x2 buffers
    __shared__ __hip_bfloat16 Vs[2][4096];
    __shared__ __hip_bfloat16 Pl[4][1280];   // per-wave 2 tiles x (16q x 32s, stride 40)

    const int lane = threadIdx.x & 63, wv = threadIdx.x >> 6;
    const int bg = blockIdx.y;                              // 0..7 : (b,g)
    const int xb = (int)blockIdx.x;
    // antisymmetric tile mapping: ids i and i+256 get tb summing to 63
    const int tb = (bg < 4) ? ((int)gridDim.x - 1 - xb) : xb;
    const int b = bg >> 2, g = bg & 3;
    const int h = g * 4 + wv;                               // this wave's q-head
    const int t0 = tb * 32;
    const int q16 = lane >> 4, r16 = lane & 15;

    const __hip_bfloat16* qh = Q + ((size_t)((b * NH_ + h) * T_) + t0) * D_;
    const __hip_bfloat16* kh = Kt + (size_t)(b * NKV_ + g) * T_ * D_;
    const __hip_bfloat16* vh = Vt + (size_t)(b * NKV_ + g) * D_ * T_;

    // Q as B-operand for both 16-q tiles: lane holds Q[q][d = kk*32 + q16*8 + j]
    bf16x8 bqA[4], bqB[4];
#pragma unroll
    for (int kk = 0; kk < 4; kk++) {
        bqA[kk] = *reinterpret_cast<const bf16x8*>(qh + (size_t)r16 * D_ + kk * 32 + q16 * 8);
        bqB[kk] = *reinterpret_cast<const bf16x8*>(qh + (size_t)(16 + r16) * D_ + kk * 32 + q16 * 8);
    }

    float liA = 0.f, liB = 0.f;
    f32x4 oA[8], oB[8];
#pragma unroll
    for (int d = 0; d < 8; d++) {
        oA[d] = (f32x4){0.f, 0.f, 0.f, 0.f};
        oB[d] = (f32x4){0.f, 0.f, 0.f, 0.f};
    }

    const float SCL2 = 0.088388347648318447f * 1.4426950408889634f;  // (1/sqrt(D)) * log2(e)
    const int tqA = t0 + r16;
    const int tqB = t0 + 16 + r16;
    const int nIter = tb + 1;   // s covered: [0, 32*(tb+1)) = [0, t0+32)

    // per-wave staging: wv 0/1 -> K halves, wv 2/3 -> V dblk quads
    const __hip_bfloat16* gK = kh + (size_t)((wv & 1) * 16 + r16) * D_ + q16 * 8;
    const __hip_bfloat16* gV = vh + (size_t)(((wv - 2) * 4) * 16 + r16) * T_ + q16 * 8;

#define STAGE(bufi, s0_)                                                        \
    do {                                                                        \
        if (wv < 2) {                                                           \
            const __hip_bfloat16* gp = gK + (size_t)(s0_) * D_;                 \
            __hip_bfloat16* lp = &Ks[bufi][(wv * 4) * 512] + lane * 8;          \
            gl_lds16(gp,      lp);                                              \
            gl_lds16(gp + 32, lp + 512);                                        \
            gl_lds16(gp + 64, lp + 1024);                                       \
            gl_lds16(gp + 96, lp + 1536);                                       \
        } else {                                                                \
            const __hip_bfloat16* gp = gV + (s0_);                              \
            __hip_bfloat16* lp = &Vs[bufi][((wv - 2) * 4) * 512] + lane * 8;    \
            gl_lds16(gp,                      lp);                              \
            gl_lds16(gp + (size_t)16 * T_,    lp + 512);                        \
            gl_lds16(gp + (size_t)32 * T_,    lp + 1024);                       \
            gl_lds16(gp + (size_t)48 * T_,    lp + 1536);                       \
        }                                                                       \
    } while (0)

    STAGE(0, 0);

    for (int it = 0; it < nIter; it++) {
        const int s0 = it * 32;
        const int cur = it & 1;
        __syncthreads();  // staging of `cur` complete; buffer `cur^1` free
        if (it + 1 < nIter) STAGE(cur ^ 1, s0 + 32);

        f32x4 sc0A = (f32x4){0.f, 0.f, 0.f, 0.f};
        f32x4 sc1A = (f32x4){0.f, 0.f, 0.f, 0.f};
        f32x4 sc0B = (f32x4){0.f, 0.f, 0.f, 0.f};
        f32x4 sc1B = (f32x4){0.f, 0.f, 0.f, 0.f};
        {
            bf16x8 ak[4];
#pragma unroll
            for (int kk = 0; kk < 4; kk++)
                ak[kk] = *reinterpret_cast<const bf16x8*>(&Ks[cur][kk * 512] + lane * 8);
#pragma unroll
            for (int kk = 0; kk < 4; kk++) {
                sc0A = __builtin_amdgcn_mfma_f32_16x16x32_bf16(ak[kk], bqA[kk], sc0A, 0, 0, 0);
                sc0B = __builtin_amdgcn_mfma_f32_16x16x32_bf16(ak[kk], bqB[kk], sc0B, 0, 0, 0);
            }
#pragma unroll
            for (int kk = 0; kk < 4; kk++)
                ak[kk] = *reinterpret_cast<const bf16x8*>(&Ks[cur][(4 + kk) * 512] + lane * 8);
#pragma unroll
            for (int kk = 0; kk < 4; kk++) {
                sc1A = __builtin_amdgcn_mfma_f32_16x16x32_bf16(ak[kk], bqA[kk], sc1A, 0, 0, 0);
                sc1B = __builtin_amdgcn_mfma_f32_16x16x32_bf16(ak[kk], bqB[kk], sc1B, 0, 0, 0);
            }
        }

        // softmax (m=0): lane owns q=r16(+16), s = s0 + q16*4 + r (+16 for sc1)
        ushort4 w0A, w1A, w0B, w1B;
        float psA = 0.f, psB = 0.f;
#pragma unroll
        for (int r = 0; r < 4; r++) {
            int s_a = s0 + q16 * 4 + r;
            float pa0 = (s_a <= tqA)      ? __builtin_amdgcn_exp2f(sc0A[r] * SCL2) : 0.f;
            float pa1 = (s_a + 16 <= tqA) ? __builtin_amdgcn_exp2f(sc1A[r] * SCL2) : 0.f;
            float pb0 = (s_a <= tqB)      ? __builtin_amdgcn_exp2f(sc0B[r] * SCL2) : 0.f;
            float pb1 = (s_a + 16 <= tqB) ? __builtin_amdgcn_exp2f(sc1B[r] * SCL2) : 0.f;
            psA += pa0 + pa1;
            psB += pb0 + pb1;
            ((unsigned short*)&w0A)[r] = (unsigned short)f2bs(pa0);
            ((unsigned short*)&w1A)[r] = (unsigned short)f2bs(pa1);
            ((unsigned short*)&w0B)[r] = (unsigned short)f2bs(pb0);
            ((unsigned short*)&w1B)[r] = (unsigned short)f2bs(pb1);
        }
        liA += psA;
        liB += psB;

        *reinterpret_cast<ushort4*>(&Pl[wv][r16 * 40 + q16 * 4]) = w0A;
        *reinterpret_cast<ushort4*>(&Pl[wv][r16 * 40 + 16 + q16 * 4]) = w1A;
        *reinterpret_cast<ushort4*>(&Pl[wv][640 + r16 * 40 + q16 * 4]) = w0B;
        *reinterpret_cast<ushort4*>(&Pl[wv][640 + r16 * 40 + 16 + q16 * 4]) = w1B;
        asm volatile("s_waitcnt lgkmcnt(0)" ::: "memory");
        bf16x8 pfA = *reinterpret_cast<const bf16x8*>(&Pl[wv][r16 * 40 + q16 * 8]);
        bf16x8 pfB = *reinterpret_cast<const bf16x8*>(&Pl[wv][640 + r16 * 40 + q16 * 8]);

#pragma unroll
        for (int d = 0; d < 8; d++) {
            bf16x8 bv = *reinterpret_cast<const bf16x8*>(&Vs[cur][d * 512] + lane * 8);
            oA[d] = __builtin_amdgcn_mfma_f32_16x16x32_bf16(pfA, bv, oA[d], 0, 0, 0);
            oB[d] = __builtin_amdgcn_mfma_f32_16x16x32_bf16(pfB, bv, oB[d], 0, 0, 0);
        }
    }

    // li partial over this lane's quad; reduce across quads
    liA += __shfl_xor(liA, 16);
    liA += __shfl_xor(liA, 32);
    liB += __shfl_xor(liB, 16);
    liB += __shfl_xor(liB, 32);
#pragma unroll
    for (int r = 0; r < 4; r++) {
        float lrA = __shfl(liA, q16 * 4 + r, 16);
        float lrB = __shfl(liB, q16 * 4 + r, 16);
        float invA = 1.0f / lrA;
        float invB = 1.0f / lrB;
        int tA = t0 + q16 * 4 + r;
        __hip_bfloat16* dstA = Ao + (size_t)(b * T_ + tA) * C_ + h * D_ + r16;
        __hip_bfloat16* dstB = dstA + (size_t)16 * C_;
#pragma unroll
        for (int d = 0; d < 8; d++) {
            dstA[d * 16] = __float2bfloat16(oA[d][r] * invA);
            dstB[d * 16] = __float2bfloat16(oB[d][r] * invB);
        }
    }
#undef STAGE
}

// ---------------- launch ----------------
extern "C" void kernel_launch(void* const* d_in, const int* in_sizes, int n_in,
                              void* d_out, int out_size, void* d_ws, size_t ws_size,
                              hipStream_t stream) {
    const float* x  = (const float*)d_in[0];
    const float* Wq = (const float*)d_in[1];
    const float* Wk = (const float*)d_in[2];
    const float* Wv = (const float*)d_in[3];
    const float* Wo = (const float*)d_in[4];
    float* out = (float*)d_out;
    char* ws = (char*)d_ws;

    __hip_bfloat16* xb   = (__hip_bfloat16*)(ws + 0);          // 16.78 MB
    __hip_bfloat16* wcat = (__hip_bfloat16*)(ws + 16777216);   // 12.58 MB
    __hip_bfloat16* wob  = (__hip_bfloat16*)(ws + 29360128);   // 8.39 MB
    __hip_bfloat16* yq   = (__hip_bfloat16*)(ws + 37748736);   // 25.17 MB
    __hip_bfloat16* qatt = (__hip_bfloat16*)(ws + 62914560);   // 16.78 MB
    __hip_bfloat16* katt = (__hip_bfloat16*)(ws + 79691776);   // 4.19 MB
    __hip_bfloat16* vT   = (__hip_bfloat16*)(ws + 83886080);   // 4.19 MB
    __hip_bfloat16* aout = (__hip_bfloat16*)(ws + 88080384);   // 16.78 MB  (total 100 MB)

    const int thr = 256;
    cvt_f32_bf16<<<(B_ * T_ * C_ / 4 + thr - 1) / thr, thr, 0, stream>>>(x, xb, B_ * T_ * C_);
    cvt_f32_bf16<<<(C_ * C_ / 4 + thr - 1) / thr, thr, 0, stream>>>(Wq, wcat, C_ * C_);
    cvt_f32_bf16<<<(512 * 2048 / 4 + thr - 1) / thr, thr, 0, stream>>>(Wk, wcat + C_ * C_, 512 * 2048);
    cvt_f32_bf16<<<(512 * 2048 / 4 + thr - 1) / thr, thr, 0, stream>>>(Wv, wcat + C_ * C_ + 512 * 2048, 512 * 2048);
    cvt_f32_bf16<<<(C_ * C_ / 4 + thr - 1) / thr, thr, 0, stream>>>(Wo, wob, C_ * C_);

    gemm_bt<__hip_bfloat16><<<dim3(24, 32), 256, 0, stream>>>(xb, wcat, yq, 4096, 3072, 2048);

    rope_scatter<<<(B_ * T_ * 1536 + thr - 1) / thr, thr, 0, stream>>>(yq, qatt, katt, vT);

    attn_kernel<<<dim3(64, 8), 256, 0, stream>>>(qatt, katt, vT, aout);

    gemm_bt<float><<<dim3(16, 32), 256, 0, stream>>>(aout, wob, out, 4096, 2048, 2048);
}

// Round 2
// 330.615 us; speedup vs baseline: 1.0629x; 1.0204x over previous
//
#include <hip/hip_runtime.h>
#include <hip/hip_bf16.h>
#include <stdint.h>

#define B_   2
#define T_   2048
#define C_   2048
#define NH_  16
#define NKV_ 4
#define D_   128
#define NREP_ 4

typedef __attribute__((ext_vector_type(8))) short bf16x8;
typedef __attribute__((ext_vector_type(4))) float f32x4;

__device__ inline short f2bs(float f) {
    __hip_bfloat16 h = __float2bfloat16(f);
    return *reinterpret_cast<short*>(&h);
}
__device__ inline float bs2f(unsigned short s) {
    __hip_bfloat16 h = *reinterpret_cast<__hip_bfloat16*>(&s);
    return __bfloat162float(h);
}

__device__ inline void gl_lds16(const __hip_bfloat16* g, __hip_bfloat16* l) {
    __builtin_amdgcn_global_load_lds(
        (const __attribute__((address_space(1))) unsigned int*)g,
        (__attribute__((address_space(3))) unsigned int*)l,
        16, 0, 0);
}

// ---------------- fp32 -> bf16 convert ----------------
__global__ void cvt_f32_bf16(const float* __restrict__ src,
                             __hip_bfloat16* __restrict__ dst, int n) {
    int i = (blockIdx.x * blockDim.x + threadIdx.x) * 4;
    if (i >= n) return;
    float4 v = *reinterpret_cast<const float4*>(src + i);
    short4 o;
    o.x = f2bs(v.x); o.y = f2bs(v.y); o.z = f2bs(v.z); o.w = f2bs(v.w);
    *reinterpret_cast<short4*>(dst + i) = o;
}

// ---------------- bf16 GEMM: C = A @ B^T (m97 structure) ----------------
__device__ inline void storeC(float* p, float v) { *p = v; }
__device__ inline void storeC(__hip_bfloat16* p, float v) { *p = __float2bfloat16(v); }

template <typename OutT>
__global__ __launch_bounds__(256) void gemm_bt(const __hip_bfloat16* __restrict__ A,
                                               const __hip_bfloat16* __restrict__ Bm,
                                               OutT* __restrict__ Cm,
                                               int M, int N, int K) {
    __shared__ __hip_bfloat16 As[128 * 32];
    __shared__ __hip_bfloat16 Bs[128 * 32];
    const int tid  = threadIdx.x;
    const int lane = tid & 63;
    const int wv   = tid >> 6;
    const int m0 = blockIdx.y * 128, n0 = blockIdx.x * 128;
    const int wm = (wv >> 1) * 64, wn = (wv & 1) * 64;
    const int q16 = lane >> 4, r16 = lane & 15;

    f32x4 acc[4][4] = {};

    const int lrow = tid >> 2;
    const int lcol = (tid & 3) * 8;
    const __hip_bfloat16* aG = A  + (size_t)(m0 + lrow) * K + lcol;
    const __hip_bfloat16* bG = Bm + (size_t)(n0 + lrow) * K + lcol;
    __hip_bfloat16* aL = As + tid * 8;
    __hip_bfloat16* bL = Bs + tid * 8;

    for (int k0 = 0; k0 < K; k0 += 32) {
        __syncthreads();
        gl_lds16(aG + k0,          aL);
        gl_lds16(aG + 64 * K + k0, aL + 2048);
        gl_lds16(bG + k0,          bL);
        gl_lds16(bG + 64 * K + k0, bL + 2048);
        __syncthreads();
        bf16x8 af[4], bfr[4];
#pragma unroll
        for (int i = 0; i < 4; i++)
            af[i] = *reinterpret_cast<const bf16x8*>(As + (wm + i * 16 + r16) * 32 + q16 * 8);
#pragma unroll
        for (int j = 0; j < 4; j++)
            bfr[j] = *reinterpret_cast<const bf16x8*>(Bs + (wn + j * 16 + r16) * 32 + q16 * 8);
#pragma unroll
        for (int i = 0; i < 4; i++)
#pragma unroll
            for (int j = 0; j < 4; j++)
                acc[i][j] = __builtin_amdgcn_mfma_f32_16x16x32_bf16(af[i], bfr[j], acc[i][j], 0, 0, 0);
    }

#pragma unroll
    for (int i = 0; i < 4; i++)
#pragma unroll
        for (int j = 0; j < 4; j++)
#pragma unroll
            for (int r = 0; r < 4; r++) {
                int row = m0 + wm + i * 16 + q16 * 4 + r;
                int col = n0 + wn + j * 16 + r16;
                storeC(&Cm[(size_t)row * N + col], acc[i][j][r]);
            }
}

// ---------------- RoPE + scatter to attention layouts ----------------
__global__ void rope_scatter(const __hip_bfloat16* __restrict__ y,
                             __hip_bfloat16* __restrict__ qo,
                             __hip_bfloat16* __restrict__ ko,
                             __hip_bfloat16* __restrict__ vT) {
    int idx = blockIdx.x * blockDim.x + threadIdx.x;
    if (idx >= (B_ * T_) * 1536) return;
    int m = idx / 1536, pc = idx % 1536;
    int b = m / T_, t = m % T_;
    int n = pc * 2;
    ushort2 uv = *reinterpret_cast<const ushort2*>(y + (size_t)m * 3072 + n);
    float e = bs2f(uv.x), od = bs2f(uv.y);

    if (n < 2560) {  // q or k: apply RoPE
        int nn = (n < 2048) ? n : (n - 2048);
        int dloc = nn & 127;
        int p = dloc >> 1;
        float inv = __expf(-(float)p * (9.210340371976184f / 64.0f));  // 10000^(-p/64)
        float ang = (float)t * inv;
        float c = cosf(ang), s = sinf(ang);
        float re = e * c - od * s;
        float ro = e * s + od * c;
        ushort2 w;
        w.x = (unsigned short)f2bs(re);
        w.y = (unsigned short)f2bs(ro);
        if (n < 2048) {
            int h = n >> 7;
            *reinterpret_cast<ushort2*>(qo + ((size_t)(b * NH_ + h) * T_ + t) * D_ + dloc) = w;
        } else {
            int h = nn >> 7;
            *reinterpret_cast<ushort2*>(ko + ((size_t)(b * NKV_ + h) * T_ + t) * D_ + dloc) = w;
        }
    } else {  // v: no rope, store transposed (d, t)
        int nn = n - 2560;
        int h = nn >> 7, d = nn & 127;
        __hip_bfloat16* base = vT + (size_t)(b * NKV_ + h) * D_ * T_;
        base[(size_t)d * T_ + t]       = __float2bfloat16(e);
        base[(size_t)(d + 1) * T_ + t] = __float2bfloat16(od);
    }
}

// ---------------- flash attention, GQA-cooperative, split-s flash-decoding ----------------
// R2 analysis: runtime ~= nIter_max * L_iter (the longest block's serial loop is the
// critical path; with ~1 wave/SIMD in the tail every latency is exposed; 77.7us/64
// iters = ~2900 cy/iter). Fix: split the s-range. m=0 softmax partials combine by pure
// ADDITION (O = sum O_s, l = sum l_s). Tiles tb>=32 are computed by TWO blocks:
//   u in [32,64): split 0, s in [0,1024), 32 iters, no causal mask needed (s<1024<=t)
//   u in [64,96): split 1, s in [1024, 32*(tb+1)), tb = u-32, 1..32 iters
// Partials are f32, stored in dead workspace regions (xb / yq); attn_combine sums,
// normalizes, writes bf16 rows t>=1024 of aout. Critical path: 64 -> 33 iters.
// Also: causal mask hoisted to a wave-uniform branch — only the diagonal iteration
// pays the 16 cmp+cndmask per lane.
__global__ __launch_bounds__(256, 3) void attn_kernel(const __hip_bfloat16* __restrict__ Q,
                                                      const __hip_bfloat16* __restrict__ Kt,
                                                      const __hip_bfloat16* __restrict__ Vt,
                                                      __hip_bfloat16* __restrict__ Ao,
                                                      float* __restrict__ O0,
                                                      float* __restrict__ O1,
                                                      float* __restrict__ l0p,
                                                      float* __restrict__ l1p) {
    __shared__ __hip_bfloat16 Ks[2][4096];   // 8 chunks x 512 shorts, x2 buffers
    __shared__ __hip_bfloat16 Vs[2][4096];
    __shared__ __hip_bfloat16 Pl[4][1280];   // per-wave 2 tiles x (16q x 32s, stride 40)

    const int lane = threadIdx.x & 63, wv = threadIdx.x >> 6;
    const int bg = blockIdx.y;                              // 0..7 : (b,g)
    const int u  = (int)blockIdx.x;                         // 0..95 work unit
    int tb, nIt, sIdx;
    if (u < 32)      { tb = u;      nIt = tb + 1;      sIdx = -1; }  // whole row range
    else if (u < 64) { tb = u;      nIt = 32;          sIdx = 0;  }  // s in [0,1024)
    else             { tb = u - 32; nIt = tb + 1 - 32; sIdx = 1;  }  // s in [1024, ...)
    const int sBase = (sIdx == 1) ? 1024 : 0;
    const int b = bg >> 2, g = bg & 3;
    const int h = g * 4 + wv;                               // this wave's q-head
    const int t0 = tb * 32;
    const int q16 = lane >> 4, r16 = lane & 15;

    const __hip_bfloat16* qh = Q + ((size_t)((b * NH_ + h) * T_) + t0) * D_;
    const __hip_bfloat16* kh = Kt + (size_t)(b * NKV_ + g) * T_ * D_;
    const __hip_bfloat16* vh = Vt + (size_t)(b * NKV_ + g) * D_ * T_;

    // Q as B-operand for both 16-q tiles: lane holds Q[q][d = kk*32 + q16*8 + j]
    bf16x8 bqA[4], bqB[4];
#pragma unroll
    for (int kk = 0; kk < 4; kk++) {
        bqA[kk] = *reinterpret_cast<const bf16x8*>(qh + (size_t)r16 * D_ + kk * 32 + q16 * 8);
        bqB[kk] = *reinterpret_cast<const bf16x8*>(qh + (size_t)(16 + r16) * D_ + kk * 32 + q16 * 8);
    }

    float liA = 0.f, liB = 0.f;
    f32x4 oA[8], oB[8];
#pragma unroll
    for (int d = 0; d < 8; d++) {
        oA[d] = (f32x4){0.f, 0.f, 0.f, 0.f};
        oB[d] = (f32x4){0.f, 0.f, 0.f, 0.f};
    }

    const float SCL2 = 0.088388347648318447f * 1.4426950408889634f;  // (1/sqrt(D)) * log2(e)
    const int tqA = t0 + r16;
    const int tqB = t0 + 16 + r16;

    // per-wave staging: wv 0/1 -> K halves, wv 2/3 -> V dblk quads
    const __hip_bfloat16* gK = kh + (size_t)((wv & 1) * 16 + r16) * D_ + q16 * 8;
    const __hip_bfloat16* gV = vh + (size_t)(((wv - 2) * 4) * 16 + r16) * T_ + q16 * 8;

#define STAGE(bufi, s0_)                                                        \
    do {                                                                        \
        if (wv < 2) {                                                           \
            const __hip_bfloat16* gp = gK + (size_t)(s0_) * D_;                 \
            __hip_bfloat16* lp = &Ks[bufi][(wv * 4) * 512] + lane * 8;          \
            gl_lds16(gp,      lp);                                              \
            gl_lds16(gp + 32, lp + 512);                                        \
            gl_lds16(gp + 64, lp + 1024);                                       \
            gl_lds16(gp + 96, lp + 1536);                                       \
        } else {                                                                \
            const __hip_bfloat16* gp = gV + (s0_);                              \
            __hip_bfloat16* lp = &Vs[bufi][((wv - 2) * 4) * 512] + lane * 8;    \
            gl_lds16(gp,                      lp);                              \
            gl_lds16(gp + (size_t)16 * T_,    lp + 512);                        \
            gl_lds16(gp + (size_t)32 * T_,    lp + 1024);                       \
            gl_lds16(gp + (size_t)48 * T_,    lp + 1536);                       \
        }                                                                       \
    } while (0)

    STAGE(0, sBase);

    for (int j = 0; j < nIt; j++) {
        const int s0 = sBase + j * 32;
        const int cur = j & 1;
        __syncthreads();  // staging of `cur` complete; buffer `cur^1` free
        if (j + 1 < nIt) STAGE(cur ^ 1, s0 + 32);

        f32x4 sc0A = (f32x4){0.f, 0.f, 0.f, 0.f};
        f32x4 sc1A = (f32x4){0.f, 0.f, 0.f, 0.f};
        f32x4 sc0B = (f32x4){0.f, 0.f, 0.f, 0.f};
        f32x4 sc1B = (f32x4){0.f, 0.f, 0.f, 0.f};
        {
            bf16x8 ak[4];
#pragma unroll
            for (int kk = 0; kk < 4; kk++)
                ak[kk] = *reinterpret_cast<const bf16x8*>(&Ks[cur][kk * 512] + lane * 8);
#pragma unroll
            for (int kk = 0; kk < 4; kk++) {
                sc0A = __builtin_amdgcn_mfma_f32_16x16x32_bf16(ak[kk], bqA[kk], sc0A, 0, 0, 0);
                sc0B = __builtin_amdgcn_mfma_f32_16x16x32_bf16(ak[kk], bqB[kk], sc0B, 0, 0, 0);
            }
#pragma unroll
            for (int kk = 0; kk < 4; kk++)
                ak[kk] = *reinterpret_cast<const bf16x8*>(&Ks[cur][(4 + kk) * 512] + lane * 8);
#pragma unroll
            for (int kk = 0; kk < 4; kk++) {
                sc1A = __builtin_amdgcn_mfma_f32_16x16x32_bf16(ak[kk], bqA[kk], sc1A, 0, 0, 0);
                sc1B = __builtin_amdgcn_mfma_f32_16x16x32_bf16(ak[kk], bqB[kk], sc1B, 0, 0, 0);
            }
        }

        // softmax (m=0): lane owns q=r16(+16), s = s0 + q16*4 + r (+16 for sc1)
        ushort4 w0A, w1A, w0B, w1B;
        float psA = 0.f, psB = 0.f;
        if (s0 + 32 > t0) {  // diagonal iteration: causal mask needed (wave-uniform branch)
#pragma unroll
            for (int r = 0; r < 4; r++) {
                int s_a = s0 + q16 * 4 + r;
                float pa0 = (s_a <= tqA)      ? __builtin_amdgcn_exp2f(sc0A[r] * SCL2) : 0.f;
                float pa1 = (s_a + 16 <= tqA) ? __builtin_amdgcn_exp2f(sc1A[r] * SCL2) : 0.f;
                float pb0 = (s_a <= tqB)      ? __builtin_amdgcn_exp2f(sc0B[r] * SCL2) : 0.f;
                float pb1 = (s_a + 16 <= tqB) ? __builtin_amdgcn_exp2f(sc1B[r] * SCL2) : 0.f;
                psA += pa0 + pa1;
                psB += pb0 + pb1;
                ((unsigned short*)&w0A)[r] = (unsigned short)f2bs(pa0);
                ((unsigned short*)&w1A)[r] = (unsigned short)f2bs(pa1);
                ((unsigned short*)&w0B)[r] = (unsigned short)f2bs(pb0);
                ((unsigned short*)&w1B)[r] = (unsigned short)f2bs(pb1);
            }
        } else {  // interior iteration: all s strictly below all q rows
#pragma unroll
            for (int r = 0; r < 4; r++) {
                float pa0 = __builtin_amdgcn_exp2f(sc0A[r] * SCL2);
                float pa1 = __builtin_amdgcn_exp2f(sc1A[r] * SCL2);
                float pb0 = __builtin_amdgcn_exp2f(sc0B[r] * SCL2);
                float pb1 = __builtin_amdgcn_exp2f(sc1B[r] * SCL2);
                psA += pa0 + pa1;
                psB += pb0 + pb1;
                ((unsigned short*)&w0A)[r] = (unsigned short)f2bs(pa0);
                ((unsigned short*)&w1A)[r] = (unsigned short)f2bs(pa1);
                ((unsigned short*)&w0B)[r] = (unsigned short)f2bs(pb0);
                ((unsigned short*)&w1B)[r] = (unsigned short)f2bs(pb1);
            }
        }
        liA += psA;
        liB += psB;

        *reinterpret_cast<ushort4*>(&Pl[wv][r16 * 40 + q16 * 4]) = w0A;
        *reinterpret_cast<ushort4*>(&Pl[wv][r16 * 40 + 16 + q16 * 4]) = w1A;
        *reinterpret_cast<ushort4*>(&Pl[wv][640 + r16 * 40 + q16 * 4]) = w0B;
        *reinterpret_cast<ushort4*>(&Pl[wv][640 + r16 * 40 + 16 + q16 * 4]) = w1B;
        asm volatile("s_waitcnt lgkmcnt(0)" ::: "memory");
        bf16x8 pfA = *reinterpret_cast<const bf16x8*>(&Pl[wv][r16 * 40 + q16 * 8]);
        bf16x8 pfB = *reinterpret_cast<const bf16x8*>(&Pl[wv][640 + r16 * 40 + q16 * 8]);

#pragma unroll
        for (int d = 0; d < 8; d++) {
            bf16x8 bv = *reinterpret_cast<const bf16x8*>(&Vs[cur][d * 512] + lane * 8);
            oA[d] = __builtin_amdgcn_mfma_f32_16x16x32_bf16(pfA, bv, oA[d], 0, 0, 0);
            oB[d] = __builtin_amdgcn_mfma_f32_16x16x32_bf16(pfB, bv, oB[d], 0, 0, 0);
        }
    }

    // li partial over this lane's quad; reduce across quads
    liA += __shfl_xor(liA, 16);
    liA += __shfl_xor(liA, 32);
    liB += __shfl_xor(liB, 16);
    liB += __shfl_xor(liB, 32);

    if (sIdx < 0) {
        // unsplit: normalize and write bf16 directly
#pragma unroll
        for (int r = 0; r < 4; r++) {
            float lrA = __shfl(liA, q16 * 4 + r, 16);
            float lrB = __shfl(liB, q16 * 4 + r, 16);
            float invA = 1.0f / lrA;
            float invB = 1.0f / lrB;
            int tA = t0 + q16 * 4 + r;
            __hip_bfloat16* dstA = Ao + (size_t)(b * T_ + tA) * C_ + h * D_ + r16;
            __hip_bfloat16* dstB = dstA + (size_t)16 * C_;
#pragma unroll
            for (int d = 0; d < 8; d++) {
                dstA[d * 16] = __float2bfloat16(oA[d][r] * invA);
                dstB[d * 16] = __float2bfloat16(oB[d][r] * invB);
            }
        }
    } else {
        // split: write unnormalized f32 partials + l partials (rows t0..t0+31, t0>=1024)
        float* Os = (sIdx == 0) ? O0 : O1;
        float* ls = (sIdx == 0) ? l0p : l1p;
        const size_t rb = (size_t)(b * NH_ + h) * 1024 + (size_t)(t0 - 1024);
        if (q16 == 0) {
            ls[rb + r16]      = liA;   // every lane holds full row-sum after the xors
            ls[rb + 16 + r16] = liB;
        }
#pragma unroll
        for (int r = 0; r < 4; r++) {
            int rowl = q16 * 4 + r;
            float* dA = Os + (rb + rowl) * 128 + r16;
            float* dB = Os + (rb + 16 + rowl) * 128 + r16;
#pragma unroll
            for (int d = 0; d < 8; d++) {
                dA[d * 16] = oA[d][r];
                dB[d * 16] = oB[d][r];
            }
        }
    }
#undef STAGE
}

// ---------------- combine split-s partials (rows t >= 1024) ----------------
__global__ void attn_combine(const float* __restrict__ O0, const float* __restrict__ O1,
                             const float* __restrict__ l0, const float* __restrict__ l1,
                             __hip_bfloat16* __restrict__ Ao) {
    int idx = blockIdx.x * blockDim.x + threadIdx.x;   // [0, 32768*32)
    int row = idx >> 5, d4 = (idx & 31) << 2;
    int bh = row >> 10, tl = row & 1023;
    int b = bh >> 4, h = bh & 15;
    float inv = 1.0f / (l0[row] + l1[row]);
    float4 a = *reinterpret_cast<const float4*>(O0 + (size_t)row * 128 + d4);
    float4 c = *reinterpret_cast<const float4*>(O1 + (size_t)row * 128 + d4);
    short4 o;
    o.x = f2bs((a.x + c.x) * inv);
    o.y = f2bs((a.y + c.y) * inv);
    o.z = f2bs((a.z + c.z) * inv);
    o.w = f2bs((a.w + c.w) * inv);
    *reinterpret_cast<short4*>(Ao + (size_t)(b * T_ + 1024 + tl) * C_ + h * D_ + d4) = o;
}

// ---------------- launch ----------------
extern "C" void kernel_launch(void* const* d_in, const int* in_sizes, int n_in,
                              void* d_out, int out_size, void* d_ws, size_t ws_size,
                              hipStream_t stream) {
    const float* x  = (const float*)d_in[0];
    const float* Wq = (const float*)d_in[1];
    const float* Wk = (const float*)d_in[2];
    const float* Wv = (const float*)d_in[3];
    const float* Wo = (const float*)d_in[4];
    float* out = (float*)d_out;
    char* ws = (char*)d_ws;

    __hip_bfloat16* xb   = (__hip_bfloat16*)(ws + 0);          // 16.78 MB (dead after GEMM1)
    __hip_bfloat16* wcat = (__hip_bfloat16*)(ws + 16777216);   // 12.58 MB (dead after GEMM1)
    __hip_bfloat16* wob  = (__hip_bfloat16*)(ws + 29360128);   // 8.39 MB  (live until GEMM2)
    __hip_bfloat16* yq   = (__hip_bfloat16*)(ws + 37748736);   // 25.17 MB (dead after rope)
    __hip_bfloat16* qatt = (__hip_bfloat16*)(ws + 62914560);   // 16.78 MB
    __hip_bfloat16* katt = (__hip_bfloat16*)(ws + 79691776);   // 4.19 MB
    __hip_bfloat16* vT   = (__hip_bfloat16*)(ws + 83886080);   // 4.19 MB
    __hip_bfloat16* aout = (__hip_bfloat16*)(ws + 88080384);   // 16.78 MB  (total 100 MB)

    // split-s partials reuse dead regions:
    float* O0 = (float*)(ws + 0);                    // 16.78 MB over xb
    float* O1 = (float*)(ws + 37748736);             // 16.78 MB over yq[0:16.78M]
    float* l0 = (float*)(ws + 37748736 + 16777216);  // 128 KB over yq tail
    float* l1 = (float*)(ws + 37748736 + 16777216 + 131072);

    const int thr = 256;
    cvt_f32_bf16<<<(B_ * T_ * C_ / 4 + thr - 1) / thr, thr, 0, stream>>>(x, xb, B_ * T_ * C_);
    cvt_f32_bf16<<<(C_ * C_ / 4 + thr - 1) / thr, thr, 0, stream>>>(Wq, wcat, C_ * C_);
    cvt_f32_bf16<<<(512 * 2048 / 4 + thr - 1) / thr, thr, 0, stream>>>(Wk, wcat + C_ * C_, 512 * 2048);
    cvt_f32_bf16<<<(512 * 2048 / 4 + thr - 1) / thr, thr, 0, stream>>>(Wv, wcat + C_ * C_ + 512 * 2048, 512 * 2048);
    cvt_f32_bf16<<<(C_ * C_ / 4 + thr - 1) / thr, thr, 0, stream>>>(Wo, wob, C_ * C_);

    gemm_bt<__hip_bfloat16><<<dim3(24, 32), 256, 0, stream>>>(xb, wcat, yq, 4096, 3072, 2048);

    rope_scatter<<<(B_ * T_ * 1536 + thr - 1) / thr, thr, 0, stream>>>(yq, qatt, katt, vT);

    attn_kernel<<<dim3(96, 8), 256, 0, stream>>>(qatt, katt, vT, aout, O0, O1, l0, l1);
    attn_combine<<<(2 * NH_ * 1024 * 32) / thr, thr, 0, stream>>>(O0, O1, l0, l1, aout);

    gemm_bt<float><<<dim3(16, 32), 256, 0, stream>>>(aout, wob, out, 4096, 2048, 2048);
}

// Round 3
// 304.617 us; speedup vs baseline: 1.1536x; 1.0853x over previous
//
#include <hip/hip_runtime.h>
#include <hip/hip_bf16.h>
#include <stdint.h>

#define B_   2
#define T_   2048
#define C_   2048
#define NH_  16
#define NKV_ 4
#define D_   128
#define NREP_ 4

typedef __attribute__((ext_vector_type(8))) short bf16x8;
typedef __attribute__((ext_vector_type(4))) float f32x4;

__device__ inline short f2bs(float f) {
    __hip_bfloat16 h = __float2bfloat16(f);
    return *reinterpret_cast<short*>(&h);
}

__device__ inline void gl_lds16(const __hip_bfloat16* g, __hip_bfloat16* l) {
    __builtin_amdgcn_global_load_lds(
        (const __attribute__((address_space(1))) unsigned int*)g,
        (__attribute__((address_space(3))) unsigned int*)l,
        16, 0, 0);
}

// ---------------- merged prep: all f32->bf16 converts + RoPE cos/sin table ----------------
// Segments (f32 elems): x 8388608 | Wq 4194304 | Wk 1048576 | Wv 1048576 | Wo 4194304
// cum: 8388608, 12582912, 13631488, 14680064, 18874368.  /4 = 4718592 cvt threads.
// Then 131072 threads build ropeTab[t*64+p] = (cos, sin)(t * 10000^(-p/64)).
__global__ void prep_kernel(const float* __restrict__ x,  const float* __restrict__ Wq,
                            const float* __restrict__ Wk, const float* __restrict__ Wv,
                            const float* __restrict__ Wo,
                            __hip_bfloat16* __restrict__ xb, __hip_bfloat16* __restrict__ wcat,
                            __hip_bfloat16* __restrict__ wob, float2* __restrict__ ropeTab) {
    int tid = blockIdx.x * blockDim.x + threadIdx.x;
    const int CVT_THREADS = 4718592;
    if (tid < CVT_THREADS) {
        int i4 = tid * 4;
        const float* src;
        __hip_bfloat16* dst;
        int off;
        if (i4 < 8388608)       { src = x;  dst = xb;             off = i4; }
        else if (i4 < 12582912) { src = Wq; dst = wcat;           off = i4 - 8388608; }
        else if (i4 < 13631488) { src = Wk; dst = wcat + 4194304; off = i4 - 12582912; }
        else if (i4 < 14680064) { src = Wv; dst = wcat + 5242880; off = i4 - 13631488; }
        else                    { src = Wo; dst = wob;            off = i4 - 14680064; }
        float4 v = *reinterpret_cast<const float4*>(src + off);
        short4 o;
        o.x = f2bs(v.x); o.y = f2bs(v.y); o.z = f2bs(v.z); o.w = f2bs(v.w);
        *reinterpret_cast<short4*>(dst + off) = o;
    } else {
        int e = tid - CVT_THREADS;
        if (e < 131072) {
            int t = e >> 6, p = e & 63;
            float inv = __expf(-(float)p * (9.210340371976184f / 64.0f));  // 10000^(-p/64)
            float ang = (float)t * inv;
            ropeTab[e] = make_float2(cosf(ang), sinf(ang));
        }
    }
}

// ---------------- bf16 GEMM: C = A @ B^T (m97 structure), plain output ----------------
__device__ inline void storeC(float* p, float v) { *p = v; }
__device__ inline void storeC(__hip_bfloat16* p, float v) { *p = __float2bfloat16(v); }

template <typename OutT>
__global__ __launch_bounds__(256) void gemm_bt(const __hip_bfloat16* __restrict__ A,
                                               const __hip_bfloat16* __restrict__ Bm,
                                               OutT* __restrict__ Cm,
                                               int M, int N, int K) {
    __shared__ __hip_bfloat16 As[128 * 32];
    __shared__ __hip_bfloat16 Bs[128 * 32];
    const int tid  = threadIdx.x;
    const int lane = tid & 63;
    const int wv   = tid >> 6;
    const int m0 = blockIdx.y * 128, n0 = blockIdx.x * 128;
    const int wm = (wv >> 1) * 64, wn = (wv & 1) * 64;
    const int q16 = lane >> 4, r16 = lane & 15;

    f32x4 acc[4][4] = {};

    const int lrow = tid >> 2;
    const int lcol = (tid & 3) * 8;
    const __hip_bfloat16* aG = A  + (size_t)(m0 + lrow) * K + lcol;
    const __hip_bfloat16* bG = Bm + (size_t)(n0 + lrow) * K + lcol;
    __hip_bfloat16* aL = As + tid * 8;
    __hip_bfloat16* bL = Bs + tid * 8;

    for (int k0 = 0; k0 < K; k0 += 32) {
        __syncthreads();
        gl_lds16(aG + k0,          aL);
        gl_lds16(aG + 64 * K + k0, aL + 2048);
        gl_lds16(bG + k0,          bL);
        gl_lds16(bG + 64 * K + k0, bL + 2048);
        __syncthreads();
        bf16x8 af[4], bfr[4];
#pragma unroll
        for (int i = 0; i < 4; i++)
            af[i] = *reinterpret_cast<const bf16x8*>(As + (wm + i * 16 + r16) * 32 + q16 * 8);
#pragma unroll
        for (int j = 0; j < 4; j++)
            bfr[j] = *reinterpret_cast<const bf16x8*>(Bs + (wn + j * 16 + r16) * 32 + q16 * 8);
#pragma unroll
        for (int i = 0; i < 4; i++)
#pragma unroll
            for (int j = 0; j < 4; j++)
                acc[i][j] = __builtin_amdgcn_mfma_f32_16x16x32_bf16(af[i], bfr[j], acc[i][j], 0, 0, 0);
    }

#pragma unroll
    for (int i = 0; i < 4; i++)
#pragma unroll
        for (int j = 0; j < 4; j++)
#pragma unroll
            for (int r = 0; r < 4; r++) {
                int row = m0 + wm + i * 16 + q16 * 4 + r;
                int col = n0 + wn + j * 16 + r16;
                storeC(&Cm[(size_t)row * N + col], acc[i][j][r]);
            }
}

// ---------------- GEMM1 with fused RoPE + q/k/v scatter epilogue ----------------
// y = x @ Wcat^T (M=4096, N=3072, K=2048). Column segments q[0,2048) k[2048,2560)
// v[2560,3072) are 128-aligned, so each 128-col block (blockIdx.x = hb) is entirely
// one head of one segment — the epilogue branch is block-uniform. RoPE pairs
// (2p, 2p+1) sit in adjacent lanes (r16 even/odd): one __shfl_xor(v,1) gives the
// partner; cos/sin come from the precomputed ropeTab (L2-resident, 1 MB).
__global__ __launch_bounds__(256) void gemm_qkv(const __hip_bfloat16* __restrict__ A,
                                                const __hip_bfloat16* __restrict__ Bm,
                                                const float2* __restrict__ ropeTab,
                                                __hip_bfloat16* __restrict__ qo,
                                                __hip_bfloat16* __restrict__ ko,
                                                __hip_bfloat16* __restrict__ vT) {
    const int K = 2048;
    __shared__ __hip_bfloat16 As[128 * 32];
    __shared__ __hip_bfloat16 Bs[128 * 32];
    const int tid  = threadIdx.x;
    const int lane = tid & 63;
    const int wv   = tid >> 6;
    const int m0 = blockIdx.y * 128, n0 = blockIdx.x * 128;
    const int wm = (wv >> 1) * 64, wn = (wv & 1) * 64;
    const int q16 = lane >> 4, r16 = lane & 15;

    f32x4 acc[4][4] = {};

    const int lrow = tid >> 2;
    const int lcol = (tid & 3) * 8;
    const __hip_bfloat16* aG = A  + (size_t)(m0 + lrow) * K + lcol;
    const __hip_bfloat16* bG = Bm + (size_t)(n0 + lrow) * K + lcol;
    __hip_bfloat16* aL = As + tid * 8;
    __hip_bfloat16* bL = Bs + tid * 8;

    for (int k0 = 0; k0 < K; k0 += 32) {
        __syncthreads();
        gl_lds16(aG + k0,          aL);
        gl_lds16(aG + 64 * K + k0, aL + 2048);
        gl_lds16(bG + k0,          bL);
        gl_lds16(bG + 64 * K + k0, bL + 2048);
        __syncthreads();
        bf16x8 af[4], bfr[4];
#pragma unroll
        for (int i = 0; i < 4; i++)
            af[i] = *reinterpret_cast<const bf16x8*>(As + (wm + i * 16 + r16) * 32 + q16 * 8);
#pragma unroll
        for (int j = 0; j < 4; j++)
            bfr[j] = *reinterpret_cast<const bf16x8*>(Bs + (wn + j * 16 + r16) * 32 + q16 * 8);
#pragma unroll
        for (int i = 0; i < 4; i++)
#pragma unroll
            for (int j = 0; j < 4; j++)
                acc[i][j] = __builtin_amdgcn_mfma_f32_16x16x32_bf16(af[i], bfr[j], acc[i][j], 0, 0, 0);
    }

    const int hb = n0 >> 7;   // 0..15 q-head | 16..19 k-head | 20..23 v-head (block-uniform)
    const float sgn = (r16 & 1) ? 1.0f : -1.0f;
#pragma unroll
    for (int i = 0; i < 4; i++)
#pragma unroll
        for (int r = 0; r < 4; r++) {
            const int m = m0 + wm + i * 16 + q16 * 4 + r;
            const int b = m >> 11, t = m & 2047;
            if (hb < 20) {  // q or k: RoPE then scatter
                const float2* tabRow = ropeTab + t * 64;
                __hip_bfloat16* dst = (hb < 16)
                    ? qo + ((size_t)(b * NH_ + hb) * T_ + t) * D_
                    : ko + ((size_t)(b * NKV_ + (hb - 16)) * T_ + t) * D_;
#pragma unroll
                for (int j = 0; j < 4; j++) {
                    const int dloc = wn + j * 16 + r16;
                    float v = acc[i][j][r];
                    float prt = __shfl_xor(v, 1);
                    float2 cs = tabRow[dloc >> 1];
                    // even lane: re = v*c - prt*s ; odd lane: ro = v*c + prt*s
                    float res = fmaf(prt * sgn, cs.y, v * cs.x);
                    dst[dloc] = __float2bfloat16(res);
                }
            } else {        // v: no rope, transposed (d, t) store
                __hip_bfloat16* dst = vT + (size_t)(b * NKV_ + (hb - 20)) * D_ * T_ + t;
#pragma unroll
                for (int j = 0; j < 4; j++) {
                    const int d = wn + j * 16 + r16;
                    dst[(size_t)d * T_] = __float2bfloat16(acc[i][j][r]);
                }
            }
        }
}

// ---------------- flash attention, GQA-cooperative, split-s flash-decoding ----------------
// Critical path = longest block's serial loop (R2). Split-s: m=0 softmax partials
// combine by pure addition. u<32: whole range (tb=u). u in [32,64): split 0,
// s in [0,1024). u in [64,96): split 1, s in [1024, 32*(tb+1)), tb=u-32.
// Causal mask hoisted to the diagonal iteration only (wave-uniform branch).
__global__ __launch_bounds__(256, 3) void attn_kernel(const __hip_bfloat16* __restrict__ Q,
                                                      const __hip_bfloat16* __restrict__ Kt,
                                                      const __hip_bfloat16* __restrict__ Vt,
                                                      __hip_bfloat16* __restrict__ Ao,
                                                      float* __restrict__ O0,
                                                      float* __restrict__ O1,
                                                      float* __restrict__ l0p,
                                                      float* __restrict__ l1p) {
    __shared__ __hip_bfloat16 Ks[2][4096];   // 8 chunks x 512 shorts, x2 buffers
    __shared__ __hip_bfloat16 Vs[2][4096];
    __shared__ __hip_bfloat16 Pl[4][1280];   // per-wave 2 tiles x (16q x 32s, stride 40)

    const int lane = threadIdx.x & 63, wv = threadIdx.x >> 6;
    const int bg = blockIdx.y;                              // 0..7 : (b,g)
    const int u  = (int)blockIdx.x;                         // 0..95 work unit
    int tb, nIt, sIdx;
    if (u < 32)      { tb = u;      nIt = tb + 1;      sIdx = -1; }  // whole row range
    else if (u < 64) { tb = u;      nIt = 32;          sIdx = 0;  }  // s in [0,1024)
    else             { tb = u - 32; nIt = tb + 1 - 32; sIdx = 1;  }  // s in [1024, ...)
    const int sBase = (sIdx == 1) ? 1024 : 0;
    const int b = bg >> 2, g = bg & 3;
    const int h = g * 4 + wv;                               // this wave's q-head
    const int t0 = tb * 32;
    const int q16 = lane >> 4, r16 = lane & 15;

    const __hip_bfloat16* qh = Q + ((size_t)((b * NH_ + h) * T_) + t0) * D_;
    const __hip_bfloat16* kh = Kt + (size_t)(b * NKV_ + g) * T_ * D_;
    const __hip_bfloat16* vh = Vt + (size_t)(b * NKV_ + g) * D_ * T_;

    // Q as B-operand for both 16-q tiles: lane holds Q[q][d = kk*32 + q16*8 + j]
    bf16x8 bqA[4], bqB[4];
#pragma unroll
    for (int kk = 0; kk < 4; kk++) {
        bqA[kk] = *reinterpret_cast<const bf16x8*>(qh + (size_t)r16 * D_ + kk * 32 + q16 * 8);
        bqB[kk] = *reinterpret_cast<const bf16x8*>(qh + (size_t)(16 + r16) * D_ + kk * 32 + q16 * 8);
    }

    float liA = 0.f, liB = 0.f;
    f32x4 oA[8], oB[8];
#pragma unroll
    for (int d = 0; d < 8; d++) {
        oA[d] = (f32x4){0.f, 0.f, 0.f, 0.f};
        oB[d] = (f32x4){0.f, 0.f, 0.f, 0.f};
    }

    const float SCL2 = 0.088388347648318447f * 1.4426950408889634f;  // (1/sqrt(D)) * log2(e)
    const int tqA = t0 + r16;
    const int tqB = t0 + 16 + r16;

    // per-wave staging: wv 0/1 -> K halves, wv 2/3 -> V dblk quads
    const __hip_bfloat16* gK = kh + (size_t)((wv & 1) * 16 + r16) * D_ + q16 * 8;
    const __hip_bfloat16* gV = vh + (size_t)(((wv - 2) * 4) * 16 + r16) * T_ + q16 * 8;

#define STAGE(bufi, s0_)                                                        \
    do {                                                                        \
        if (wv < 2) {                                                           \
            const __hip_bfloat16* gp = gK + (size_t)(s0_) * D_;                 \
            __hip_bfloat16* lp = &Ks[bufi][(wv * 4) * 512] + lane * 8;          \
            gl_lds16(gp,      lp);                                              \
            gl_lds16(gp + 32, lp + 512);                                        \
            gl_lds16(gp + 64, lp + 1024);                                       \
            gl_lds16(gp + 96, lp + 1536);                                      \
        } else {                                                                \
            const __hip_bfloat16* gp = gV + (s0_);                              \
            __hip_bfloat16* lp = &Vs[bufi][((wv - 2) * 4) * 512] + lane * 8;    \
            gl_lds16(gp,                      lp);                              \
            gl_lds16(gp + (size_t)16 * T_,    lp + 512);                        \
            gl_lds16(gp + (size_t)32 * T_,    lp + 1024);                       \
            gl_lds16(gp + (size_t)48 * T_,    lp + 1536);                       \
        }                                                                       \
    } while (0)

    STAGE(0, sBase);

    for (int j = 0; j < nIt; j++) {
        const int s0 = sBase + j * 32;
        const int cur = j & 1;
        __syncthreads();  // staging of `cur` complete; buffer `cur^1` free
        if (j + 1 < nIt) STAGE(cur ^ 1, s0 + 32);

        f32x4 sc0A = (f32x4){0.f, 0.f, 0.f, 0.f};
        f32x4 sc1A = (f32x4){0.f, 0.f, 0.f, 0.f};
        f32x4 sc0B = (f32x4){0.f, 0.f, 0.f, 0.f};
        f32x4 sc1B = (f32x4){0.f, 0.f, 0.f, 0.f};
        {
            bf16x8 ak[4];
#pragma unroll
            for (int kk = 0; kk < 4; kk++)
                ak[kk] = *reinterpret_cast<const bf16x8*>(&Ks[cur][kk * 512] + lane * 8);
#pragma unroll
            for (int kk = 0; kk < 4; kk++) {
                sc0A = __builtin_amdgcn_mfma_f32_16x16x32_bf16(ak[kk], bqA[kk], sc0A, 0, 0, 0);
                sc0B = __builtin_amdgcn_mfma_f32_16x16x32_bf16(ak[kk], bqB[kk], sc0B, 0, 0, 0);
            }
#pragma unroll
            for (int kk = 0; kk < 4; kk++)
                ak[kk] = *reinterpret_cast<const bf16x8*>(&Ks[cur][(4 + kk) * 512] + lane * 8);
#pragma unroll
            for (int kk = 0; kk < 4; kk++) {
                sc1A = __builtin_amdgcn_mfma_f32_16x16x32_bf16(ak[kk], bqA[kk], sc1A, 0, 0, 0);
                sc1B = __builtin_amdgcn_mfma_f32_16x16x32_bf16(ak[kk], bqB[kk], sc1B, 0, 0, 0);
            }
        }

        // softmax (m=0): lane owns q=r16(+16), s = s0 + q16*4 + r (+16 for sc1)
        ushort4 w0A, w1A, w0B, w1B;
        float psA = 0.f, psB = 0.f;
        if (s0 + 32 > t0) {  // diagonal iteration: causal mask needed (wave-uniform branch)
#pragma unroll
            for (int r = 0; r < 4; r++) {
                int s_a = s0 + q16 * 4 + r;
                float pa0 = (s_a <= tqA)      ? __builtin_amdgcn_exp2f(sc0A[r] * SCL2) : 0.f;
                float pa1 = (s_a + 16 <= tqA) ? __builtin_amdgcn_exp2f(sc1A[r] * SCL2) : 0.f;
                float pb0 = (s_a <= tqB)      ? __builtin_amdgcn_exp2f(sc0B[r] * SCL2) : 0.f;
                float pb1 = (s_a + 16 <= tqB) ? __builtin_amdgcn_exp2f(sc1B[r] * SCL2) : 0.f;
                psA += pa0 + pa1;
                psB += pb0 + pb1;
                ((unsigned short*)&w0A)[r] = (unsigned short)f2bs(pa0);
                ((unsigned short*)&w1A)[r] = (unsigned short)f2bs(pa1);
                ((unsigned short*)&w0B)[r] = (unsigned short)f2bs(pb0);
                ((unsigned short*)&w1B)[r] = (unsigned short)f2bs(pb1);
            }
        } else {  // interior iteration: all s strictly below all q rows
#pragma unroll
            for (int r = 0; r < 4; r++) {
                float pa0 = __builtin_amdgcn_exp2f(sc0A[r] * SCL2);
                float pa1 = __builtin_amdgcn_exp2f(sc1A[r] * SCL2);
                float pb0 = __builtin_amdgcn_exp2f(sc0B[r] * SCL2);
                float pb1 = __builtin_amdgcn_exp2f(sc1B[r] * SCL2);
                psA += pa0 + pa1;
                psB += pb0 + pb1;
                ((unsigned short*)&w0A)[r] = (unsigned short)f2bs(pa0);
                ((unsigned short*)&w1A)[r] = (unsigned short)f2bs(pa1);
                ((unsigned short*)&w0B)[r] = (unsigned short)f2bs(pb0);
                ((unsigned short*)&w1B)[r] = (unsigned short)f2bs(pb1);
            }
        }
        liA += psA;
        liB += psB;

        *reinterpret_cast<ushort4*>(&Pl[wv][r16 * 40 + q16 * 4]) = w0A;
        *reinterpret_cast<ushort4*>(&Pl[wv][r16 * 40 + 16 + q16 * 4]) = w1A;
        *reinterpret_cast<ushort4*>(&Pl[wv][640 + r16 * 40 + q16 * 4]) = w0B;
        *reinterpret_cast<ushort4*>(&Pl[wv][640 + r16 * 40 + 16 + q16 * 4]) = w1B;
        asm volatile("s_waitcnt lgkmcnt(0)" ::: "memory");
        bf16x8 pfA = *reinterpret_cast<const bf16x8*>(&Pl[wv][r16 * 40 + q16 * 8]);
        bf16x8 pfB = *reinterpret_cast<const bf16x8*>(&Pl[wv][640 + r16 * 40 + q16 * 8]);

#pragma unroll
        for (int d = 0; d < 8; d++) {
            bf16x8 bv = *reinterpret_cast<const bf16x8*>(&Vs[cur][d * 512] + lane * 8);
            oA[d] = __builtin_amdgcn_mfma_f32_16x16x32_bf16(pfA, bv, oA[d], 0, 0, 0);
            oB[d] = __builtin_amdgcn_mfma_f32_16x16x32_bf16(pfB, bv, oB[d], 0, 0, 0);
        }
    }

    // li partial over this lane's quad; reduce across quads
    liA += __shfl_xor(liA, 16);
    liA += __shfl_xor(liA, 32);
    liB += __shfl_xor(liB, 16);
    liB += __shfl_xor(liB, 32);

    if (sIdx < 0) {
        // unsplit: normalize and write bf16 directly
#pragma unroll
        for (int r = 0; r < 4; r++) {
            float lrA = __shfl(liA, q16 * 4 + r, 16);
            float lrB = __shfl(liB, q16 * 4 + r, 16);
            float invA = 1.0f / lrA;
            float invB = 1.0f / lrB;
            int tA = t0 + q16 * 4 + r;
            __hip_bfloat16* dstA = Ao + (size_t)(b * T_ + tA) * C_ + h * D_ + r16;
            __hip_bfloat16* dstB = dstA + (size_t)16 * C_;
#pragma unroll
            for (int d = 0; d < 8; d++) {
                dstA[d * 16] = __float2bfloat16(oA[d][r] * invA);
                dstB[d * 16] = __float2bfloat16(oB[d][r] * invB);
            }
        }
    } else {
        // split: write unnormalized f32 partials + l partials (rows t0..t0+31, t0>=1024)
        float* Os = (sIdx == 0) ? O0 : O1;
        float* ls = (sIdx == 0) ? l0p : l1p;
        const size_t rb = (size_t)(b * NH_ + h) * 1024 + (size_t)(t0 - 1024);
        if (q16 == 0) {
            ls[rb + r16]      = liA;   // every lane holds full row-sum after the xors
            ls[rb + 16 + r16] = liB;
        }
#pragma unroll
        for (int r = 0; r < 4; r++) {
            int rowl = q16 * 4 + r;
            float* dA = Os + (rb + rowl) * 128 + r16;
            float* dB = Os + (rb + 16 + rowl) * 128 + r16;
#pragma unroll
            for (int d = 0; d < 8; d++) {
                dA[d * 16] = oA[d][r];
                dB[d * 16] = oB[d][r];
            }
        }
    }
#undef STAGE
}

// ---------------- combine split-s partials (rows t >= 1024) ----------------
__global__ void attn_combine(const float* __restrict__ O0, const float* __restrict__ O1,
                             const float* __restrict__ l0, const float* __restrict__ l1,
                             __hip_bfloat16* __restrict__ Ao) {
    int idx = blockIdx.x * blockDim.x + threadIdx.x;   // [0, 32768*32)
    int row = idx >> 5, d4 = (idx & 31) << 2;
    int bh = row >> 10, tl = row & 1023;
    int b = bh >> 4, h = bh & 15;
    float inv = 1.0f / (l0[row] + l1[row]);
    float4 a = *reinterpret_cast<const float4*>(O0 + (size_t)row * 128 + d4);
    float4 c = *reinterpret_cast<const float4*>(O1 + (size_t)row * 128 + d4);
    short4 o;
    o.x = f2bs((a.x + c.x) * inv);
    o.y = f2bs((a.y + c.y) * inv);
    o.z = f2bs((a.z + c.z) * inv);
    o.w = f2bs((a.w + c.w) * inv);
    *reinterpret_cast<short4*>(Ao + (size_t)(b * T_ + 1024 + tl) * C_ + h * D_ + d4) = o;
}

// ---------------- launch ----------------
extern "C" void kernel_launch(void* const* d_in, const int* in_sizes, int n_in,
                              void* d_out, int out_size, void* d_ws, size_t ws_size,
                              hipStream_t stream) {
    const float* x  = (const float*)d_in[0];
    const float* Wq = (const float*)d_in[1];
    const float* Wk = (const float*)d_in[2];
    const float* Wv = (const float*)d_in[3];
    const float* Wo = (const float*)d_in[4];
    float* out = (float*)d_out;
    char* ws = (char*)d_ws;

    // layout (bytes). xb/wcat/ropeTab dead after gemm_qkv; O0 overlays xb.
    __hip_bfloat16* xb   = (__hip_bfloat16*)(ws + 0);          // 16.78 MB
    __hip_bfloat16* wcat = (__hip_bfloat16*)(ws + 16777216);   // 12.58 MB
    float2*         ropeTab = (float2*)(ws + 29360128);        // 1.05 MB
    __hip_bfloat16* wob  = (__hip_bfloat16*)(ws + 30408704);   // 8.39 MB (live until GEMM2)
    __hip_bfloat16* qatt = (__hip_bfloat16*)(ws + 38797312);   // 16.78 MB
    __hip_bfloat16* katt = (__hip_bfloat16*)(ws + 55574528);   // 4.19 MB
    __hip_bfloat16* vT   = (__hip_bfloat16*)(ws + 59768832);   // 4.19 MB
    __hip_bfloat16* aout = (__hip_bfloat16*)(ws + 63963136);   // 16.78 MB
    float* O0 = (float*)(ws + 0);                              // overlays dead xb
    float* O1 = (float*)(ws + 80740352);                       // 16.78 MB
    float* l0 = (float*)(ws + 97517568);                       // 128 KB
    float* l1 = (float*)(ws + 97648640);                       // 128 KB (end ~97.8 MB)

    const int thr = 256;
    prep_kernel<<<18944, thr, 0, stream>>>(x, Wq, Wk, Wv, Wo, xb, wcat, wob, ropeTab);

    gemm_qkv<<<dim3(24, 32), 256, 0, stream>>>(xb, wcat, ropeTab, qatt, katt, vT);

    attn_kernel<<<dim3(96, 8), 256, 0, stream>>>(qatt, katt, vT, aout, O0, O1, l0, l1);
    attn_combine<<<(2 * NH_ * 1024 * 32) / thr, thr, 0, stream>>>(O0, O1, l0, l1, aout);

    gemm_bt<float><<<dim3(16, 32), 256, 0, stream>>>(aout, wob, out, 4096, 2048, 2048);
}